// Round 8
// baseline (459.731 us; speedup 1.0000x reference)
//
#include <hip/hip_runtime.h>
#include <hip/hip_fp16.h>

#define N_NODES 50000
#define DIM 64
#define CB 196          // coarse buckets = ceil(N/256); bucket = dst >> 8
#define CAP 5120        // per-bucket capacity (mean 4096, sd ~64 -> +16 sd)
#define EPT 4           // edges per thread in partition kernel
#define PADW 68         // pooled LDS row stride (+4 floats: bank spread)

typedef _Float16 half8 __attribute__((ext_vector_type(8)));
typedef _Float16 half4v __attribute__((ext_vector_type(4)));
typedef float floatx4 __attribute__((ext_vector_type(4)));

// Workspace byte offsets (16B-aligned).
#define WS_CURSOR  0                          // CB ints (1 KB reserved)
#define WS_COARSE  1024                       // CB*CAP uint = 4,014,080
#define WS_XH      (WS_COARSE + 4014080)      // N*DIM f16 = 6,400,000
#define WS_POOLED  (WS_XH + 6400000)          // N*DIM f16 = 6,400,000
#define WS_WT      (WS_POOLED + 6400000)      // DIM*DIM f16 = 8,192

// ---------------------------------------------------------------------------
// Kernel 0: x -> xh (fp16); block 3125 builds W^T fp16 and zeroes cursor.
// ---------------------------------------------------------------------------
__global__ void __launch_bounds__(256) convert_kernel(
        const float* __restrict__ x, const float* __restrict__ W,
        _Float16* __restrict__ xh, _Float16* __restrict__ wt,
        int* __restrict__ bucket_cursor) {
    int b = blockIdx.x, t = threadIdx.x;
    if (b < 3125) {
        int i = b * 256 + t;                  // one float4 per thread
        float4 v = reinterpret_cast<const float4*>(x)[i];
        half4v h = { (_Float16)v.x, (_Float16)v.y, (_Float16)v.z, (_Float16)v.w };
        reinterpret_cast<half4v*>(xh)[i] = h;
    } else {
        if (t < CB) bucket_cursor[t] = 0;
        #pragma unroll
        for (int i = 0; i < 16; ++i) {        // W^T: wt[n*64+k] = W[k*64+n]
            int idx = t * 16 + i;
            int n = idx >> 6, k = idx & 63;
            wt[idx] = (_Float16)W[k * DIM + n];
        }
    }
}

// ---------------------------------------------------------------------------
// Phase A: partition edges into coarse buckets. Edge packed as (src<<8)|loc.
// ---------------------------------------------------------------------------
__global__ void __launch_bounds__(256) partition_kernel(
        const int* __restrict__ edge_src,
        const int* __restrict__ edge_dst,
        int* __restrict__ bucket_cursor,
        unsigned int* __restrict__ coarse,
        int E) {
    __shared__ int lhist[CB];
    __shared__ int lbase[CB];
    int t = threadIdx.x;
    for (int i = t; i < CB; i += 256) lhist[i] = 0;
    __syncthreads();

    int base_e = blockIdx.x * (256 * EPT);
    unsigned int pk[EPT];
    int bk[EPT];
    #pragma unroll
    for (int j = 0; j < EPT; ++j) {
        int e = base_e + j * 256 + t;
        bk[j] = -1;
        if (e < E) {
            int s = edge_src[e];
            int d = edge_dst[e];
            bk[j] = d >> 8;
            pk[j] = ((unsigned int)s << 8) | (unsigned int)(d & 255);
            atomicAdd(&lhist[bk[j]], 1);
        }
    }
    __syncthreads();

    for (int i = t; i < CB; i += 256) {
        lbase[i] = atomicAdd(&bucket_cursor[i], lhist[i]);
        lhist[i] = 0;
    }
    __syncthreads();

    #pragma unroll
    for (int j = 0; j < EPT; ++j) {
        if (bk[j] >= 0) {
            int r = atomicAdd(&lhist[bk[j]], 1);
            coarse[(size_t)bk[j] * CAP + lbase[bk[j]] + r] = pk[j];
        }
    }
}

// ---------------------------------------------------------------------------
// Phase B (fused sort+gather): one block per coarse bucket. The 256-node
// pooled tile lives in LDS (fp32, stride 68 to spread banks by 4*(loc%8));
// init with residual x rows, stream the bucket's packed edges (8 edges in
// flight per wave, half8 gather), accumulate via LDS atomicAdd (ds_add_f32,
// one wave-instr per edge), then emit fp16 pooled rows for the MFMA stage.
// No sort, no CSR, no global sorted_src round-trip.
// ---------------------------------------------------------------------------
__global__ void __launch_bounds__(512) aggregate_kernel(
        const float* __restrict__ x,
        const _Float16* __restrict__ xh,
        const int* __restrict__ bucket_cursor,
        const unsigned int* __restrict__ coarse,
        _Float16* __restrict__ pooled) {
    __shared__ float pl[256 * PADW];
    int t = threadIdx.x;
    int b = blockIdx.x;
    int nb = b * 256;

    // Init: residual self-connection. 4096 float4s / 512 threads = 8 each.
    #pragma unroll
    for (int r = 0; r < 8; ++r) {
        int idx = t + 512 * r;               // float4 index in tile
        int loc = idx >> 4, c4 = idx & 15;
        int node = nb + loc;
        if (node < N_NODES) {
            float4 v = reinterpret_cast<const float4*>(x)[(size_t)node * 16 + c4];
            float* p = &pl[loc * PADW + c4 * 4];
            p[0] = v.x; p[1] = v.y; p[2] = v.z; p[3] = v.w;
        }
    }
    __syncthreads();

    int cnt = bucket_cursor[b];
    const unsigned int* cb = coarse + (size_t)b * CAP;
    int w = t >> 6, lane = t & 63;
    int s = lane >> 3, c = lane & 7;

    for (int base = w * 64; base < cnt; base += 512) {
        unsigned int id = 0;
        if (base + lane < cnt) id = cb[base + lane];
        #pragma unroll
        for (int k = 0; k < 8; ++k) {
            int ei = s * 8 + k;
            unsigned int e = __shfl(id, ei);
            if (base + ei < cnt) {
                int src = (int)(e >> 8);
                int loc = (int)(e & 255u);
                half8 v = *reinterpret_cast<const half8*>(
                    xh + (size_t)src * DIM + c * 8);
                float* p = &pl[loc * PADW + c * 8];
                #pragma unroll
                for (int j = 0; j < 8; ++j) atomicAdd(&p[j], (float)v[j]);
            }
        }
    }
    __syncthreads();

    // Emit fp16 pooled rows. 2048 half8s / 512 threads = 4 each.
    #pragma unroll
    for (int r = 0; r < 4; ++r) {
        int idx = t + 512 * r;               // half8 index in tile
        int loc = idx >> 3, cp = idx & 7;
        int node = nb + loc;
        if (node < N_NODES) {
            const float* p = &pl[loc * PADW + cp * 8];
            half8 o;
            #pragma unroll
            for (int j = 0; j < 8; ++j) o[j] = (_Float16)p[j];
            *reinterpret_cast<half8*>(pooled + (size_t)node * DIM + cp * 8) = o;
        }
    }
}

// ---------------------------------------------------------------------------
// Projection on the matrix pipe: pooled(50000x64 f16) @ W(64x64 f16) via
// mfma_f32_16x16x32_f16, + bias, /deg, ReLU.  One wave = 16 nodes x 64 cols.
// A[m=lane&15][k=q*8+j]; B frags contiguous from W^T; C/D: col=lane&15,
// row=q*4+reg.
// ---------------------------------------------------------------------------
__global__ void __launch_bounds__(256) project_mfma_kernel(
        const _Float16* __restrict__ pooled,
        const _Float16* __restrict__ wt,
        const float* __restrict__ bias,
        const float* __restrict__ deg,
        float* __restrict__ out) {
    int t = threadIdx.x;
    int lane = t & 63;
    int m = lane & 15;
    int q = lane >> 4;
    int nb = blockIdx.x * 64 + (t >> 6) * 16;
    if (nb >= N_NODES) return;     // N multiple of 16 -> whole wave-tile valid

    half8 a0 = *reinterpret_cast<const half8*>(pooled + (size_t)(nb + m) * DIM + q * 8);
    half8 a1 = *reinterpret_cast<const half8*>(pooled + (size_t)(nb + m) * DIM + q * 8 + 32);

    floatx4 acc[4];
    #pragma unroll
    for (int tt = 0; tt < 4; ++tt) {
        half8 b0 = *reinterpret_cast<const half8*>(wt + (size_t)(tt * 16 + m) * DIM + q * 8);
        half8 b1 = *reinterpret_cast<const half8*>(wt + (size_t)(tt * 16 + m) * DIM + q * 8 + 32);
        floatx4 cfrag = {0.f, 0.f, 0.f, 0.f};
        cfrag = __builtin_amdgcn_mfma_f32_16x16x32_f16(a0, b0, cfrag, 0, 0, 0);
        cfrag = __builtin_amdgcn_mfma_f32_16x16x32_f16(a1, b1, cfrag, 0, 0, 0);
        acc[tt] = cfrag;
    }

    #pragma unroll
    for (int r = 0; r < 4; ++r) {
        int row = q * 4 + r;
        float inv = 1.0f / deg[nb + row];
        #pragma unroll
        for (int tt = 0; tt < 4; ++tt) {
            float v = (acc[tt][r] + bias[tt * 16 + m]) * inv;
            out[(size_t)(nb + row) * DIM + tt * 16 + m] = fmaxf(v, 0.f);
        }
    }
}

extern "C" void kernel_launch(void* const* d_in, const int* in_sizes, int n_in,
                              void* d_out, int out_size, void* d_ws, size_t ws_size,
                              hipStream_t stream) {
    const float* x        = (const float*)d_in[0];
    const float* weight   = (const float*)d_in[1];
    const float* bias     = (const float*)d_in[2];
    const float* node_deg = (const float*)d_in[3];
    const int*   edge_src = (const int*)d_in[4];
    const int*   edge_dst = (const int*)d_in[5];
    float* out = (float*)d_out;
    const int E = in_sizes[4];

    char* ws = (char*)d_ws;
    int*          bucket_cursor = (int*)(ws + WS_CURSOR);
    unsigned int* coarse        = (unsigned int*)(ws + WS_COARSE);
    _Float16*     xh            = (_Float16*)(ws + WS_XH);
    _Float16*     pooled        = (_Float16*)(ws + WS_POOLED);
    _Float16*     wt            = (_Float16*)(ws + WS_WT);

    convert_kernel<<<3126, 256, 0, stream>>>(x, weight, xh, wt, bucket_cursor);

    int pa_blocks = (E + 256 * EPT - 1) / (256 * EPT);   // 782
    partition_kernel<<<pa_blocks, 256, 0, stream>>>(
        edge_src, edge_dst, bucket_cursor, coarse, E);

    aggregate_kernel<<<CB, 512, 0, stream>>>(
        x, xh, bucket_cursor, coarse, pooled);

    project_mfma_kernel<<<(N_NODES + 63) / 64, 256, 0, stream>>>(
        pooled, wt, bias, node_deg, out);
}

// Round 9
// 124.896 us; speedup vs baseline: 3.6809x; 3.6809x over previous
//
#include <hip/hip_runtime.h>
#include <hip/hip_fp16.h>

#define N_NODES 50000
#define DIM 64
#define CB 391          // coarse buckets = ceil(N/128); bucket = dst >> 7
#define BNODES 128      // nodes per bucket
#define CAP 2560        // per-bucket capacity (mean 2046, sd ~45 -> +11 sd)
#define EPT 4           // edges per thread in partition kernel
#define PLW 68          // pooled LDS row stride in floats (+4: bank spread)

typedef _Float16 half8 __attribute__((ext_vector_type(8)));
typedef _Float16 half4v __attribute__((ext_vector_type(4)));
typedef float floatx4 __attribute__((ext_vector_type(4)));

// Workspace byte offsets (16B-aligned).
#define WS_CURSOR  0                          // CB ints (2 KB reserved)
#define WS_COARSE  2048                       // CB*CAP uint = 4,003,840
#define WS_XH      (WS_COARSE + 4003840)      // N*DIM f16 = 6,400,000
#define WS_WT      (WS_XH + 6400000)          // DIM*DIM f16 = 8,192

// ---------------------------------------------------------------------------
// Kernel 0: x -> xh (fp16); block 3125 builds W^T fp16 and zeroes cursor.
// ---------------------------------------------------------------------------
__global__ void __launch_bounds__(256) convert_kernel(
        const float* __restrict__ x, const float* __restrict__ W,
        _Float16* __restrict__ xh, _Float16* __restrict__ wt,
        int* __restrict__ bucket_cursor) {
    int b = blockIdx.x, t = threadIdx.x;
    if (b < 3125) {
        int i = b * 256 + t;                  // one float4 per thread
        float4 v = reinterpret_cast<const float4*>(x)[i];
        half4v h = { (_Float16)v.x, (_Float16)v.y, (_Float16)v.z, (_Float16)v.w };
        reinterpret_cast<half4v*>(xh)[i] = h;
    } else {
        for (int i = t; i < CB; i += 256) bucket_cursor[i] = 0;
        #pragma unroll
        for (int i = 0; i < 16; ++i) {        // W^T: wt[n*64+k] = W[k*64+n]
            int idx = t * 16 + i;
            int n = idx >> 6, k = idx & 63;
            wt[idx] = (_Float16)W[k * DIM + n];
        }
    }
}

// ---------------------------------------------------------------------------
// Phase A: partition edges into coarse buckets. Edge packed as (src<<7)|loc,
// loc = dst & 127 (src < 2^16 -> fits 23 bits).
// ---------------------------------------------------------------------------
__global__ void __launch_bounds__(256) partition_kernel(
        const int* __restrict__ edge_src,
        const int* __restrict__ edge_dst,
        int* __restrict__ bucket_cursor,
        unsigned int* __restrict__ coarse,
        int E) {
    __shared__ int lhist[CB];
    __shared__ int lbase[CB];
    int t = threadIdx.x;
    for (int i = t; i < CB; i += 256) lhist[i] = 0;
    __syncthreads();

    int base_e = blockIdx.x * (256 * EPT);
    unsigned int pk[EPT];
    int bk[EPT];
    #pragma unroll
    for (int j = 0; j < EPT; ++j) {
        int e = base_e + j * 256 + t;
        bk[j] = -1;
        if (e < E) {
            int s = edge_src[e];
            int d = edge_dst[e];
            bk[j] = d >> 7;
            pk[j] = ((unsigned int)s << 7) | (unsigned int)(d & 127);
            atomicAdd(&lhist[bk[j]], 1);
        }
    }
    __syncthreads();

    for (int i = t; i < CB; i += 256) {
        lbase[i] = atomicAdd(&bucket_cursor[i], lhist[i]);
        lhist[i] = 0;
    }
    __syncthreads();

    #pragma unroll
    for (int j = 0; j < EPT; ++j) {
        if (bk[j] >= 0) {
            int r = atomicAdd(&lhist[bk[j]], 1);
            coarse[(size_t)bk[j] * CAP + lbase[bk[j]] + r] = pk[j];
        }
    }
}

// ---------------------------------------------------------------------------
// Phase B (fused sort + gather + project): one 512-thread block per bucket.
//  1. LDS counting-sort the bucket's ~2048 edges by local dst (src into
//     sedges[]) — int atomics only, 2 LDS ops/edge.
//  2. 64 groups x 8 lanes: each group owns nodes loc=g and g+64.  Edge ids
//     come from sedges via broadcast ds_read (same addr across the group =
//     conflict-free, no shfl).  half8 gather from xh, fp32 register
//     accumulate + residual, ONE plain ds_write of the pooled row into a
//     stride-68 fp32 LDS tile (each node written by exactly one group).
//  3. Each wave projects 16 nodes: A-frags from the LDS tile (fp32->f16),
//     B-frags contiguous from W^T, 2x mfma_f32_16x16x32_f16 per N-tile,
//     fused bias + /deg + ReLU -> out.  No pooled global round-trip.
// ---------------------------------------------------------------------------
__global__ void __launch_bounds__(512) fused_kernel(
        const float* __restrict__ x,
        const _Float16* __restrict__ xh,
        const _Float16* __restrict__ wt,
        const float* __restrict__ bias,
        const float* __restrict__ deg,
        const int* __restrict__ bucket_cursor,
        const unsigned int* __restrict__ coarse,
        float* __restrict__ out) {
    __shared__ unsigned int sedges[CAP];
    __shared__ float pl[BNODES * PLW];
    __shared__ int hist[BNODES];
    __shared__ int excl[BNODES];
    __shared__ int cur[BNODES];

    int t = threadIdx.x;
    int b = blockIdx.x;
    int nb = b * BNODES;
    int cnt = bucket_cursor[b];
    const unsigned int* cbk = coarse + (size_t)b * CAP;

    // --- 1a. histogram over 128 local bins ---
    if (t < BNODES) hist[t] = 0;
    __syncthreads();
    for (int i = t; i < cnt; i += 512) {
        atomicAdd(&hist[cbk[i] & 127u], 1);
    }
    __syncthreads();

    // --- 1b. exclusive scan of 128 bins (Hillis-Steele, first 128 thr) ---
    if (t < BNODES) excl[t] = hist[t];
    __syncthreads();
    #pragma unroll
    for (int off = 1; off < BNODES; off <<= 1) {
        int u = 0;
        if (t < BNODES && t >= off) u = excl[t - off];
        __syncthreads();
        if (t < BNODES) excl[t] += u;
        __syncthreads();
    }
    if (t < BNODES) {
        int ex = excl[t] - hist[t];
        excl[t] = ex;
        cur[t]  = ex;
    }
    __syncthreads();

    // --- 1c. scatter src ids into locally-sorted order (re-read from L2) ---
    for (int i = t; i < cnt; i += 512) {
        unsigned int e = cbk[i];
        int p = atomicAdd(&cur[e & 127u], 1);
        sedges[p] = e >> 7;
    }
    __syncthreads();

    // --- 2. gather: 64 groups of 8 lanes, 2 nodes per group ---
    int g = t >> 3;          // group 0..63
    int c = t & 7;           // half8 chunk within the row
    #pragma unroll
    for (int pass = 0; pass < 2; ++pass) {
        int loc = g + pass * 64;
        int node = nb + loc;
        float acc[8];
        #pragma unroll
        for (int j = 0; j < 8; ++j) acc[j] = 0.f;
        int off = excl[loc];
        int ct = (node < N_NODES) ? hist[loc] : 0;
        for (int k = 0; k < ct; ++k) {
            int src = (int)sedges[off + k];          // broadcast ds_read
            half8 v = *reinterpret_cast<const half8*>(
                xh + (size_t)src * DIM + c * 8);
            #pragma unroll
            for (int j = 0; j < 8; ++j) acc[j] += (float)v[j];
        }
        if (node < N_NODES) {
            const float4 r0 = *reinterpret_cast<const float4*>(
                x + (size_t)node * DIM + c * 8);
            const float4 r1 = *reinterpret_cast<const float4*>(
                x + (size_t)node * DIM + c * 8 + 4);
            float* p = &pl[loc * PLW + c * 8];
            p[0] = acc[0] + r0.x; p[1] = acc[1] + r0.y;
            p[2] = acc[2] + r0.z; p[3] = acc[3] + r0.w;
            p[4] = acc[4] + r1.x; p[5] = acc[5] + r1.y;
            p[6] = acc[6] + r1.z; p[7] = acc[7] + r1.w;
        }
    }
    __syncthreads();

    // --- 3. MFMA projection: wave wv handles nodes lbase..lbase+15 ---
    int wv = t >> 6;
    int lane = t & 63;
    int m = lane & 15;
    int q = lane >> 4;
    int lbase = wv * 16;

    const float* ap = &pl[(lbase + m) * PLW];
    half8 a0, a1;
    #pragma unroll
    for (int j = 0; j < 8; ++j) a0[j] = (_Float16)ap[q * 8 + j];
    #pragma unroll
    for (int j = 0; j < 8; ++j) a1[j] = (_Float16)ap[32 + q * 8 + j];

    floatx4 acc4[4];
    #pragma unroll
    for (int tt = 0; tt < 4; ++tt) {
        half8 b0 = *reinterpret_cast<const half8*>(wt + (size_t)(tt * 16 + m) * DIM + q * 8);
        half8 b1 = *reinterpret_cast<const half8*>(wt + (size_t)(tt * 16 + m) * DIM + q * 8 + 32);
        floatx4 cfrag = {0.f, 0.f, 0.f, 0.f};
        cfrag = __builtin_amdgcn_mfma_f32_16x16x32_f16(a0, b0, cfrag, 0, 0, 0);
        cfrag = __builtin_amdgcn_mfma_f32_16x16x32_f16(a1, b1, cfrag, 0, 0, 0);
        acc4[tt] = cfrag;
    }

    #pragma unroll
    for (int r = 0; r < 4; ++r) {
        int row = q * 4 + r;
        int node = nb + lbase + row;
        if (node < N_NODES) {
            float inv = 1.0f / deg[node];
            #pragma unroll
            for (int tt = 0; tt < 4; ++tt) {
                float v = (acc4[tt][r] + bias[tt * 16 + m]) * inv;
                out[(size_t)node * DIM + tt * 16 + m] = fmaxf(v, 0.f);
            }
        }
    }
}

extern "C" void kernel_launch(void* const* d_in, const int* in_sizes, int n_in,
                              void* d_out, int out_size, void* d_ws, size_t ws_size,
                              hipStream_t stream) {
    const float* x        = (const float*)d_in[0];
    const float* weight   = (const float*)d_in[1];
    const float* bias     = (const float*)d_in[2];
    const float* node_deg = (const float*)d_in[3];
    const int*   edge_src = (const int*)d_in[4];
    const int*   edge_dst = (const int*)d_in[5];
    float* out = (float*)d_out;
    const int E = in_sizes[4];

    char* ws = (char*)d_ws;
    int*          bucket_cursor = (int*)(ws + WS_CURSOR);
    unsigned int* coarse        = (unsigned int*)(ws + WS_COARSE);
    _Float16*     xh            = (_Float16*)(ws + WS_XH);
    _Float16*     wt            = (_Float16*)(ws + WS_WT);

    convert_kernel<<<3126, 256, 0, stream>>>(x, weight, xh, wt, bucket_cursor);

    int pa_blocks = (E + 256 * EPT - 1) / (256 * EPT);   // 782
    partition_kernel<<<pa_blocks, 256, 0, stream>>>(
        edge_src, edge_dst, bucket_cursor, coarse, E);

    fused_kernel<<<CB, 512, 0, stream>>>(
        x, xh, wt, bias, node_deg, bucket_cursor, coarse, out);
}

// Round 10
// 120.089 us; speedup vs baseline: 3.8283x; 1.0400x over previous
//
#include <hip/hip_runtime.h>
#include <hip/hip_fp16.h>

#define N_NODES 50000
#define DIM 64
#define CB 391          // coarse buckets = ceil(N/128); bucket = dst >> 7
#define CAP 2560        // per-bucket capacity (mean 2046, sd ~45 -> +11 sd)
#define EB 6400         // edges per partition block (256 thr x 25)
#define PLW 68          // pooled LDS row stride in floats (+4: bank spread)
#define SCAP 1344       // per-half-bucket LDS edge capacity (mean 1023, +10 sd)

typedef _Float16 half8 __attribute__((ext_vector_type(8)));
typedef _Float16 half4v __attribute__((ext_vector_type(4)));
typedef float floatx4 __attribute__((ext_vector_type(4)));

// Workspace byte offsets (16B-aligned).
#define WS_CURSOR  0                          // CB ints (2 KB reserved)
#define WS_COARSE  2048                       // CB*CAP uint = 4,003,840
#define WS_XH      (WS_COARSE + 4003840)      // N*DIM f16 = 6,400,000
#define WS_WT      (WS_XH + 6400000)          // DIM*DIM f16 = 8,192

// ---------------------------------------------------------------------------
// Prep kernel (merged): blocks [0,pa) partition edges into coarse buckets
// (two-pass: hist, reserve, re-read+scatter -> per-block runs of ~16 edges
// = 64 B for write-combining); blocks [pa, pa+3125) convert x -> fp16;
// last block builds W^T fp16.  All block ranges independent.
// ---------------------------------------------------------------------------
__global__ void __launch_bounds__(256) prep_kernel(
        const float* __restrict__ x, const float* __restrict__ W,
        const int* __restrict__ edge_src, const int* __restrict__ edge_dst,
        _Float16* __restrict__ xh, _Float16* __restrict__ wt,
        int* __restrict__ bucket_cursor, unsigned int* __restrict__ coarse,
        int E, int pa) {
    int b = blockIdx.x, t = threadIdx.x;
    if (b < pa) {
        __shared__ int lhist[CB];
        __shared__ int lbase[CB];
        for (int i = t; i < CB; i += 256) lhist[i] = 0;
        __syncthreads();

        int base = b * EB;
        int end = base + EB; if (end > E) end = E;

        for (int i = base + t; i < end; i += 256) {
            atomicAdd(&lhist[edge_dst[i] >> 7], 1);
        }
        __syncthreads();
        for (int i = t; i < CB; i += 256) {
            lbase[i] = atomicAdd(&bucket_cursor[i], lhist[i]);
            lhist[i] = 0;
        }
        __syncthreads();
        for (int i = base + t; i < end; i += 256) {
            int s = edge_src[i];
            int d = edge_dst[i];
            int bk = d >> 7;
            int r = atomicAdd(&lhist[bk], 1);
            coarse[(size_t)bk * CAP + lbase[bk] + r] =
                ((unsigned int)s << 7) | (unsigned int)(d & 127);
        }
    } else if (b < pa + 3125) {
        int i = (b - pa) * 256 + t;           // one float4 per thread
        float4 v = reinterpret_cast<const float4*>(x)[i];
        half4v h = { (_Float16)v.x, (_Float16)v.y, (_Float16)v.z, (_Float16)v.w };
        reinterpret_cast<half4v*>(xh)[i] = h;
    } else {
        #pragma unroll
        for (int i = 0; i < 16; ++i) {        // W^T: wt[n*64+k] = W[k*64+n]
            int idx = t * 16 + i;
            int n = idx >> 6, k = idx & 63;
            wt[idx] = (_Float16)W[k * DIM + n];
        }
    }
}

// ---------------------------------------------------------------------------
// Fused sort + gather + project.  TWO 256-thread blocks per bucket (grid 782
// ~ 3.05 blocks/CU: fixes the 391-block 2x makespan imbalance).  Block b
// owns the 64 nodes [b*64, b*64+64):
//  1. Filter the bucket's packed edges to our half; 64-bin LDS hist +
//     barrier-free wave shfl-scan + scatter into sedges (int atomics only).
//  2. 32 groups x 8 lanes, 2 nodes/group: broadcast ds_read of edge id,
//     half8 gather from xh (4-wide unrolled -> 4x MLP), fp32 register
//     accumulate + residual, one plain ds_write per pooled row (stride 68).
//  3. 4 waves x 16 nodes: mfma_f32_16x16x32_f16 from LDS tile + W^T, fused
//     bias + /deg + ReLU -> out.  No global pooled round-trip.
// ---------------------------------------------------------------------------
__global__ void __launch_bounds__(256) fused_kernel(
        const float* __restrict__ x,
        const _Float16* __restrict__ xh,
        const _Float16* __restrict__ wt,
        const float* __restrict__ bias,
        const float* __restrict__ deg,
        const int* __restrict__ bucket_cursor,
        const unsigned int* __restrict__ coarse,
        float* __restrict__ out) {
    __shared__ unsigned int sedges[SCAP];
    __shared__ float pl[64 * PLW];
    __shared__ int hist[64];
    __shared__ int excl[64];
    __shared__ int cur[64];

    int t = threadIdx.x;
    int b = blockIdx.x;
    int bucket = b >> 1;
    int half = b & 1;
    int nb = b * 64;                       // global node base for this block
    int cnt = bucket_cursor[bucket];
    const unsigned int* cbk = coarse + (size_t)bucket * CAP;

    // --- 1a. histogram over our 64 local bins ---
    if (t < 64) hist[t] = 0;
    __syncthreads();
    for (int i = t; i < cnt; i += 256) {
        unsigned int e = cbk[i];
        int loc = (int)(e & 127u);
        if ((loc >> 6) == half) atomicAdd(&hist[loc & 63], 1);
    }
    __syncthreads();

    // --- 1b. wave shfl-scan (threads 0..63 = wave 0), no barrier loop ---
    if (t < 64) {
        int v = hist[t];
        int s = v;
        #pragma unroll
        for (int off = 1; off < 64; off <<= 1) {
            int u = __shfl_up(s, off);
            if (t >= off) s += u;
        }
        excl[t] = s - v;
        cur[t]  = s - v;
    }
    __syncthreads();

    // --- 1c. scatter src ids into locally-sorted order ---
    for (int i = t; i < cnt; i += 256) {
        unsigned int e = cbk[i];
        int loc = (int)(e & 127u);
        if ((loc >> 6) == half) {
            int p = atomicAdd(&cur[loc & 63], 1);
            sedges[p] = e >> 7;
        }
    }
    __syncthreads();

    // --- 2. gather: 32 groups of 8 lanes, 2 nodes per group ---
    int g = t >> 3;          // group 0..31
    int c = t & 7;           // half8 chunk within the row
    #pragma unroll
    for (int pass = 0; pass < 2; ++pass) {
        int loc = g + pass * 32;
        int node = nb + loc;
        float acc[8];
        #pragma unroll
        for (int j = 0; j < 8; ++j) acc[j] = 0.f;
        int off = excl[loc];
        int ct = (node < N_NODES) ? hist[loc] : 0;
        int k = 0;
        for (; k + 4 <= ct; k += 4) {       // 4 edges in flight
            int s0 = (int)sedges[off + k + 0];
            int s1 = (int)sedges[off + k + 1];
            int s2 = (int)sedges[off + k + 2];
            int s3 = (int)sedges[off + k + 3];
            half8 v0 = *reinterpret_cast<const half8*>(xh + (size_t)s0 * DIM + c * 8);
            half8 v1 = *reinterpret_cast<const half8*>(xh + (size_t)s1 * DIM + c * 8);
            half8 v2 = *reinterpret_cast<const half8*>(xh + (size_t)s2 * DIM + c * 8);
            half8 v3 = *reinterpret_cast<const half8*>(xh + (size_t)s3 * DIM + c * 8);
            #pragma unroll
            for (int j = 0; j < 8; ++j) {
                acc[j] += (float)v0[j]; acc[j] += (float)v1[j];
                acc[j] += (float)v2[j]; acc[j] += (float)v3[j];
            }
        }
        for (; k < ct; ++k) {
            int s0 = (int)sedges[off + k];
            half8 v0 = *reinterpret_cast<const half8*>(xh + (size_t)s0 * DIM + c * 8);
            #pragma unroll
            for (int j = 0; j < 8; ++j) acc[j] += (float)v0[j];
        }
        if (node < N_NODES) {
            const float4 r0 = *reinterpret_cast<const float4*>(
                x + (size_t)node * DIM + c * 8);
            const float4 r1 = *reinterpret_cast<const float4*>(
                x + (size_t)node * DIM + c * 8 + 4);
            float* p = &pl[loc * PLW + c * 8];
            p[0] = acc[0] + r0.x; p[1] = acc[1] + r0.y;
            p[2] = acc[2] + r0.z; p[3] = acc[3] + r0.w;
            p[4] = acc[4] + r1.x; p[5] = acc[5] + r1.y;
            p[6] = acc[6] + r1.z; p[7] = acc[7] + r1.w;
        }
    }
    __syncthreads();

    // --- 3. MFMA projection: wave wv handles nodes lbase..lbase+15 ---
    int wv = t >> 6;
    int lane = t & 63;
    int m = lane & 15;
    int q = lane >> 4;
    int lbase = wv * 16;

    const float* ap = &pl[(lbase + m) * PLW];
    half8 a0, a1;
    #pragma unroll
    for (int j = 0; j < 8; ++j) a0[j] = (_Float16)ap[q * 8 + j];
    #pragma unroll
    for (int j = 0; j < 8; ++j) a1[j] = (_Float16)ap[32 + q * 8 + j];

    floatx4 acc4[4];
    #pragma unroll
    for (int tt = 0; tt < 4; ++tt) {
        half8 b0 = *reinterpret_cast<const half8*>(wt + (size_t)(tt * 16 + m) * DIM + q * 8);
        half8 b1 = *reinterpret_cast<const half8*>(wt + (size_t)(tt * 16 + m) * DIM + q * 8 + 32);
        floatx4 cfrag = {0.f, 0.f, 0.f, 0.f};
        cfrag = __builtin_amdgcn_mfma_f32_16x16x32_f16(a0, b0, cfrag, 0, 0, 0);
        cfrag = __builtin_amdgcn_mfma_f32_16x16x32_f16(a1, b1, cfrag, 0, 0, 0);
        acc4[tt] = cfrag;
    }

    #pragma unroll
    for (int r = 0; r < 4; ++r) {
        int row = q * 4 + r;
        int node = nb + lbase + row;
        if (node < N_NODES) {
            float inv = 1.0f / deg[node];
            #pragma unroll
            for (int tt = 0; tt < 4; ++tt) {
                float v = (acc4[tt][r] + bias[tt * 16 + m]) * inv;
                out[(size_t)node * DIM + tt * 16 + m] = fmaxf(v, 0.f);
            }
        }
    }
}

extern "C" void kernel_launch(void* const* d_in, const int* in_sizes, int n_in,
                              void* d_out, int out_size, void* d_ws, size_t ws_size,
                              hipStream_t stream) {
    const float* x        = (const float*)d_in[0];
    const float* weight   = (const float*)d_in[1];
    const float* bias     = (const float*)d_in[2];
    const float* node_deg = (const float*)d_in[3];
    const int*   edge_src = (const int*)d_in[4];
    const int*   edge_dst = (const int*)d_in[5];
    float* out = (float*)d_out;
    const int E = in_sizes[4];

    char* ws = (char*)d_ws;
    int*          bucket_cursor = (int*)(ws + WS_CURSOR);
    unsigned int* coarse        = (unsigned int*)(ws + WS_COARSE);
    _Float16*     xh            = (_Float16*)(ws + WS_XH);
    _Float16*     wt            = (_Float16*)(ws + WS_WT);

    hipMemsetAsync(bucket_cursor, 0, CB * sizeof(int), stream);

    int pa = (E + EB - 1) / EB;               // 125 partition blocks
    prep_kernel<<<pa + 3125 + 1, 256, 0, stream>>>(
        x, weight, edge_src, edge_dst, xh, wt, bucket_cursor, coarse, E, pa);

    fused_kernel<<<2 * CB, 256, 0, stream>>>(
        x, xh, wt, bias, node_deg, bucket_cursor, coarse, out);
}